// Round 16
// baseline (152.803 us; speedup 1.0000x reference)
//
#include <hip/hip_runtime.h>
#include <hip/hip_bf16.h>
#include <cstdint>
#include <cmath>

#define EPSV 1e-6f
#define PSTR 1183744

typedef __attribute__((ext_vector_type(8))) short bf16x8;
typedef __attribute__((ext_vector_type(4))) float f32x4;

__device__ __forceinline__ short f2b(float f) {
  unsigned u = __float_as_uint(f);
  u = (u + 0x7fffu + ((u >> 16) & 1u)) >> 16;   // RNE fp32 -> bf16
  return (short)u;
}

__device__ __forceinline__ bf16x8 cvt8(float4 a, float4 b) {
  bf16x8 v;
  v[0]=f2b(a.x); v[1]=f2b(a.y); v[2]=f2b(a.z); v[3]=f2b(a.w);
  v[4]=f2b(b.x); v[5]=f2b(b.y); v[6]=f2b(b.z); v[7]=f2b(b.w);
  return v;
}

// fp32 -> bf16 bulk convert (for the small A matrix)
__global__ __launch_bounds__(256) void conv_bf16(
    const float* __restrict__ in, short* __restrict__ out, int n8) {
  const int i = blockIdx.x * 256 + threadIdx.x;
  if (i < n8) {
    float4 a = ((const float4*)in)[2 * i];
    float4 b = ((const float4*)in)[2 * i + 1];
    ((bf16x8*)out)[i] = cvt8(a, b);
  }
}

// inline-asm loads: "=&v" outputs force the allocator to keep every load
// result live from issue to consumption. R8 retro: with the DEFAULT
// register budget the allocator got only 56 VGPR for a ~78-reg live set
// and spilled the asm outputs to scratch (spill-store waits its load ->
// serialized stream). Fix: __launch_bounds__(256, 3) -> ~168 VGPR budget,
// zero spill, still 12 waves/CU = 192 KB in flight (>> 9.2 KB BW*latency).
#define GLOAD4(dst, base) \
  asm volatile("global_load_dwordx4 %0, %1, off" : "=&v"(dst) : "v"(base) : "memory")
#define GLOAD4O(dst, base, OFF) \
  asm volatile("global_load_dwordx4 %0, %1, off offset:" #OFF \
               : "=&v"(dst) : "v"(base) : "memory")

// Outp[ks][64][N] = Abf[64,K-slice] @ W[N,K-slice]^T  (bf16 MFMA, fp32 W)
// No LDS, no barriers. Per wave: 32m x 16n strip, k-slice of NT 64-wide
// tiles. Register double-buffer, depth-2 counted vmcnt(8) pipeline.
template<int KSPLIT, int NT>
__global__ __launch_bounds__(256, 3) void gemm_stream3(
    const short* __restrict__ Abf, const float* __restrict__ W,
    float* __restrict__ Outp, int N, int K) {
  const int lane = threadIdx.x & 63;
  const int wv = threadIdx.x >> 6;
  const int lrow = lane & 15, lk = lane >> 4;
  const int bid = blockIdx.x;
  const int ks = bid % KSPLIT;
  const int n0 = (bid / KSPLIT) * 32 + (wv & 1) * 16;   // wave's n-strip
  const int m0 = (wv >> 1) * 32;                        // wave's m-half
  const int kb = ks * (NT * 64);

  const float* wp = W + (size_t)(n0 + lrow) * K + kb + lk * 8;
  const short* a0 = Abf + (size_t)(m0 + lrow) * K + kb + lk * 8;
  const short* a1 = a0 + (size_t)16 * K;

  float4 w[2][4];    // [buf][kc0_lo,kc0_hi,kc1_lo,kc1_hi]  (fp32 W)
  float4 av[2][4];   // [buf][mf0kc0,mf0kc1,mf1kc0,mf1kc1]  (bf16x8 bits)
  f32x4 acc0 = {0.f,0.f,0.f,0.f}, acc1 = {0.f,0.f,0.f,0.f};

#define ISSUE(B) do { \
    GLOAD4 (w[B][0], wp);            GLOAD4O(w[B][1], wp, 16); \
    GLOAD4O(w[B][2], wp, 128);       GLOAD4O(w[B][3], wp, 144); \
    GLOAD4 (av[B][0], a0);           GLOAD4O(av[B][1], a0, 64); \
    GLOAD4 (av[B][2], a1);           GLOAD4O(av[B][3], a1, 64); \
    wp += 64; a0 += 64; a1 += 64; \
  } while (0)

#define TILE(B) do { \
    const bf16x8 wb0 = cvt8(w[B][0], w[B][1]); \
    const bf16x8 wb1 = cvt8(w[B][2], w[B][3]); \
    acc0 = __builtin_amdgcn_mfma_f32_16x16x32_bf16(__builtin_bit_cast(bf16x8, av[B][0]), wb0, acc0, 0, 0, 0); \
    acc0 = __builtin_amdgcn_mfma_f32_16x16x32_bf16(__builtin_bit_cast(bf16x8, av[B][1]), wb1, acc0, 0, 0, 0); \
    acc1 = __builtin_amdgcn_mfma_f32_16x16x32_bf16(__builtin_bit_cast(bf16x8, av[B][2]), wb0, acc1, 0, 0, 0); \
    acc1 = __builtin_amdgcn_mfma_f32_16x16x32_bf16(__builtin_bit_cast(bf16x8, av[B][3]), wb1, acc1, 0, 0, 0); \
  } while (0)

  ISSUE(0);
  for (int t = 0; t < NT; t += 2) {
    // even tile -> buf0
    if (t + 1 < NT) { ISSUE(1);
                      asm volatile("s_waitcnt vmcnt(8)" ::: "memory"); }
    else            { asm volatile("s_waitcnt vmcnt(0)" ::: "memory"); }
    __builtin_amdgcn_sched_barrier(0);
    TILE(0);
    if (t + 1 >= NT) break;
    // odd tile -> buf1
    if (t + 2 < NT) { ISSUE(0);
                      asm volatile("s_waitcnt vmcnt(8)" ::: "memory"); }
    else            { asm volatile("s_waitcnt vmcnt(0)" ::: "memory"); }
    __builtin_amdgcn_sched_barrier(0);
    TILE(1);
  }
#undef ISSUE
#undef TILE

  // C/D layout: col(lane&15)=n, row=(lane>>4)*4+i=m  [m89-verified]
  float* ob = Outp + (size_t)ks * 64 * N + n0 + lrow;
#pragma unroll
  for (int i = 0; i < 4; ++i) {
    ob[(size_t)(m0 + lk * 4 + i) * N]      = acc0[i];
    ob[(size_t)(m0 + 16 + lk * 4 + i) * N] = acc1[i];
  }
}

__device__ __forceinline__ float block_reduce_sum256(float v, float* red, int t) {
#pragma unroll
  for (int o = 32; o > 0; o >>= 1) v += __shfl_xor(v, o, 64);
  __syncthreads();
  if ((t & 63) == 0) red[t >> 6] = v;
  __syncthreads();
  return red[0] + red[1] + red[2] + red[3];
}

// one block per (b, head); 256 threads. proj = pp0 + pp1 (split-K partials).
__global__ __launch_bounds__(256) void state_update(
    const float* __restrict__ pp0, const float* __restrict__ pp1,
    const float* __restrict__ h,
    const float* __restrict__ B_prev, const float* __restrict__ x_prev,
    const float* __restrict__ theta_cumsum, const float* __restrict__ A_log,
    const float* __restrict__ B_bias, const float* __restrict__ C_bias,
    float* __restrict__ o_h, float* __restrict__ o_B,
    float* __restrict__ o_xp, float* __restrict__ o_th,
    short* __restrict__ ysbf) {
  const int bid = blockIdx.x;            // b*32 + hd
  const int b = bid >> 5, hd = bid & 31;
  const int t = threadIdx.x;
  const size_t pb = (size_t)b * 18496;
#define PJ(o) (pp0[pb + (o)] + pp1[pb + (o)])

  __shared__ float sB[128], sC[128], sBp[128], sXp[128], sXv[128];
  __shared__ float red[8];
  __shared__ float yred[8][128];

  float aval = (t < 128) ? expf(A_log[hd * 128 + t]) : 0.f;
  float brv  = (t < 128) ? PJ(8192 + hd * 128 + t) : 0.f;
  float crv  = (t < 128) ? PJ(12288 + hd * 128 + t) : 0.f;
  if (t < 128) {
    sBp[t] = B_prev[(size_t)bid * 128 + t];
    float xp = PJ(hd * 128 + t);
    sXp[t] = xp;
    o_xp[(size_t)bid * 128 + t] = xp;
    sXv[t] = x_prev[(size_t)bid * 128 + t];
  }
  float sumA  = block_reduce_sum256(aval, red, t);
  float sumB2 = block_reduce_sum256(brv * brv, red, t);
  float sumC2 = block_reduce_sum256(crv * crv, red, t);

  const float dt_raw  = PJ(16384 + hd);
  const float lam_raw = PJ(16416 + hd);
  const float dt  = (dt_raw > 20.f) ? dt_raw : log1pf(expf(dt_raw));
  const float lam = 1.f / (1.f + expf(-lam_raw));
  const float A     = -sumA * (1.f / 128.f);
  const float alpha = expf(dt * A);
  const float beta  = (1.f - lam) * dt * alpha;
  const float gamma = lam * dt;
  const float rb = rsqrtf(sumB2 * (1.f / 128.f) + EPSV);
  const float rc = rsqrtf(sumC2 * (1.f / 128.f) + EPSV);

  if (t < 64) {
    float b0 = PJ(8192 + hd * 128 + 2 * t);
    float b1 = PJ(8192 + hd * 128 + 2 * t + 1);
    float c0 = PJ(12288 + hd * 128 + 2 * t);
    float c1 = PJ(12288 + hd * 128 + 2 * t + 1);
    b0 = b0 * rb + B_bias[hd * 128 + 2 * t];
    b1 = b1 * rb + B_bias[hd * 128 + 2 * t + 1];
    c0 = c0 * rc + C_bias[hd * 128 + 2 * t];
    c1 = c1 * rc + C_bias[hd * 128 + 2 * t + 1];
    const float th = theta_cumsum[(size_t)bid * 64 + t]
                   + PJ(16448 + hd * 64 + t) * dt;
    o_th[(size_t)bid * 64 + t] = th;
    const float cth = cosf(th), sth = sinf(th);
    const float nb0 = b0 * cth - b1 * sth, nb1 = b0 * sth + b1 * cth;
    const float nc0 = c0 * cth - c1 * sth, nc1 = c0 * sth + c1 * cth;
    sB[2 * t] = nb0; sB[2 * t + 1] = nb1;
    sC[2 * t] = nc0; sC[2 * t + 1] = nc1;
    o_B[(size_t)bid * 128 + 2 * t] = nb0;
    o_B[(size_t)bid * 128 + 2 * t + 1] = nb1;
  }
  __syncthreads();

  const int p4 = t & 31, nb = t >> 5;
  const float4 xp4 = *(const float4*)&sXp[p4 * 4];
  const float4 xv4 = *(const float4*)&sXv[p4 * 4];
  const size_t hbase = (size_t)bid * 16384;
  float4 ya = {0.f, 0.f, 0.f, 0.f};
#pragma unroll 4
  for (int n = nb; n < 128; n += 8) {
    const float4 hv = *(const float4*)&h[hbase + n * 128 + p4 * 4];
    const float cb = gamma * sB[n];
    const float cp = beta * sBp[n];
    float4 hn;
    hn.x = alpha * hv.x + cp * xv4.x + cb * xp4.x;
    hn.y = alpha * hv.y + cp * xv4.y + cb * xp4.y;
    hn.z = alpha * hv.z + cp * xv4.z + cb * xp4.z;
    hn.w = alpha * hv.w + cp * xv4.w + cb * xp4.w;
    *(float4*)&o_h[hbase + n * 128 + p4 * 4] = hn;
    const float cn = sC[n];
    ya.x += cn * hn.x; ya.y += cn * hn.y; ya.z += cn * hn.z; ya.w += cn * hn.w;
  }
  *(float4*)&yred[nb][p4 * 4] = ya;
  __syncthreads();
  if (t < 128) {
    float y = 0.f;
#pragma unroll
    for (int j = 0; j < 8; ++j) y += yred[j][t];
    const float zv = PJ(4096 + hd * 128 + t);
    const float sig = 1.f / (1.f + expf(-zv));
    ysbf[(size_t)b * 4096 + hd * 128 + t] = f2b(y * zv * sig);
  }
#undef PJ
}

// y[64][2048] = sum over 8 K-split partials
__global__ __launch_bounds__(256) void reduce_y(
    const float* __restrict__ yp, float* __restrict__ y, int n4) {
  const int i = blockIdx.x * 256 + threadIdx.x;
  if (i < n4) {
    float4 s = ((const float4*)yp)[i];
#pragma unroll
    for (int k = 1; k < 8; ++k) {
      float4 t = ((const float4*)(yp + (size_t)k * 131072))[i];
      s.x += t.x; s.y += t.y; s.z += t.z; s.w += t.w;
    }
    ((float4*)y)[i] = s;
  }
}

extern "C" void kernel_launch(void* const* d_in, const int* in_sizes, int n_in,
                              void* d_out, int out_size, void* d_ws, size_t ws_size,
                              hipStream_t stream) {
  const float* x            = (const float*)d_in[0];
  const float* h            = (const float*)d_in[1];
  const float* B_prev       = (const float*)d_in[2];
  const float* x_prev       = (const float*)d_in[3];
  const float* theta_cumsum = (const float*)d_in[4];
  const float* W_in         = (const float*)d_in[5];
  const float* A_log        = (const float*)d_in[6];
  const float* B_bias       = (const float*)d_in[7];
  const float* C_bias       = (const float*)d_in[8];
  const float* W_out        = (const float*)d_in[9];

  float* out  = (float*)d_out;
  float* o_y  = out;                        // 64*2048
  float* o_h  = out + 131072;               // 64*32*128*128
  float* o_B  = o_h + 33554432;             // 64*32*128
  float* o_xp = o_B + 262144;               // 64*32*128
  float* o_th = o_xp + 262144;              // 64*32*64

  // ws layout
  float* pp   = (float*)d_ws;               // 2 x PSTR fp32 split-K partials
  float* yp   = pp;                         // 8 x 131072 fp32 (reuse after SU)
  short* xbf  = (short*)(pp + 2 * PSTR);    // 64*2048 bf16
  short* ysbf = xbf + 131072;               // 64*4096 bf16

  // 1) x -> bf16
  conv_bf16<<<dim3(64), dim3(256), 0, stream>>>(x, xbf, 16384);
  // 2) proj partials = xbf @ W_in^T   (N=18496, K=2048, split-K=2, NT=16)
  gemm_stream3<2, 16><<<dim3(578 * 2), dim3(256), 0, stream>>>(
      xbf, W_in, pp, 18496, 2048);
  // 3) fused state update (sums the 2 partials at load)
  state_update<<<dim3(2048), dim3(256), 0, stream>>>(
      pp, pp + PSTR, h, B_prev, x_prev, theta_cumsum, A_log, B_bias, C_bias,
      o_h, o_B, o_xp, o_th, ysbf);
  // 4) y partials = ysbf @ W_out^T    (N=2048, K=4096, split-K=8, NT=8)
  gemm_stream3<8, 8><<<dim3(64 * 8), dim3(256), 0, stream>>>(
      ysbf, W_out, yp, 2048, 4096);
  // 5) final y reduce
  reduce_y<<<dim3(128), dim3(256), 0, stream>>>(yp, o_y, 32768);
}

// Round 17
// 118.234 us; speedup vs baseline: 1.2924x; 1.2924x over previous
//
#include <hip/hip_runtime.h>
#include <hip/hip_bf16.h>
#include <cstdint>
#include <cmath>

#define EPSV 1e-6f
#define PSTR 1183744

typedef __attribute__((ext_vector_type(8))) short bf16x8;
typedef __attribute__((ext_vector_type(4))) float f32x4;

typedef __attribute__((address_space(3))) unsigned int lds_u32;
typedef const __attribute__((address_space(1))) unsigned int g_u32;

__device__ __forceinline__ void load_lds16(const void* g, void* l) {
  // DMA 16B/lane; LDS dest = wave-uniform base + lane*16 (linear)
  __builtin_amdgcn_global_load_lds((g_u32*)g, (lds_u32*)l, 16, 0, 0);
}

__device__ __forceinline__ short f2b(float f) {
  unsigned u = __float_as_uint(f);
  u = (u + 0x7fffu + ((u >> 16) & 1u)) >> 16;   // RNE fp32 -> bf16
  return (short)u;
}

__device__ __forceinline__ bf16x8 cvt8(float4 a, float4 b) {
  bf16x8 v;
  v[0]=f2b(a.x); v[1]=f2b(a.y); v[2]=f2b(a.z); v[3]=f2b(a.w);
  v[4]=f2b(b.x); v[5]=f2b(b.y); v[6]=f2b(b.z); v[7]=f2b(b.w);
  return v;
}

__global__ __launch_bounds__(256) void conv_bf16(
    const float* __restrict__ in, short* __restrict__ out, int n8) {
  const int i = blockIdx.x * 256 + threadIdx.x;
  if (i < n8) {
    float4 a = ((const float4*)in)[2 * i];
    float4 b = ((const float4*)in)[2 * i + 1];
    ((bf16x8*)out)[i] = cvt8(a, b);
  }
}

// Outp[ks][64][N] = Abf[64,K-slice] @ W[N,K-slice]^T   (bf16 MFMA)
// R11 deep-DMA pipeline, ONE change: waitcnt asms have NO "memory"
// clobber. R16 disproved the spill theory (big VGPR budget, same 87us)
// -> the clobber itself was the saboteur: LLVM's waitcnt pass orders
// memory-clobber asm against outstanding VMEM by draining vmcnt first,
// so every "counted" wait was secretly vmcnt(0) (and R4==R3 within 7us,
// R8==R16 -- both explained). asm volatile blocks keep mutual order;
// sched_barrier(0) pins compiler ds_reads/MFMAs below the wait (rule 18).
template<int KSPLIT, int NT>
__global__ __launch_bounds__(256, 2) void gemm_wlds(
    const short* __restrict__ Abf, const float* __restrict__ W,
    float* __restrict__ Outp, int N, int K) {
  __shared__ float Wlds[3][64 * 64];   // [buf][row 0..63][64 k fp32], swz ^(r&15)
  __shared__ short Alds[3][64 * 64];   // [buf][row 0..63][64 k bf16], swz ^(r&7)
  const int tid = threadIdx.x;
  const int lane = tid & 63;
  const int wv = tid >> 6;
  const int lrow = lane & 15, lk = lane >> 4;
  const int bid = blockIdx.x;
  const int ks = bid % KSPLIT;
  const int nblk = (bid / KSPLIT) * 64;
  const int kbase = ks * (NT * 64);

  f32x4 acc[4];
#pragma unroll
  for (int i = 0; i < 4; ++i) acc[i] = (f32x4){0.f, 0.f, 0.f, 0.f};

  auto stage = [&](int buf, int k0) {
    // W: 4 instr/thread; instr covers 1KB LDS = 4 rows x 256B
#pragma unroll
    for (int j = 0; j < 4; ++j) {
      const int c = wv * 4 + j;                  // 1KB chunk 0..15
      const int r = c * 4 + (lane >> 4);         // local n-row 0..63
      const int g = (lane & 15) ^ (r & 15);      // pre-swizzled src granule
      load_lds16(W + (size_t)(nblk + r) * K + k0 + g * 4,
                 (char*)&Wlds[buf][0] + c * 1024);
    }
    // A: 2 instr/thread; instr covers 1KB LDS = 8 rows x 128B
#pragma unroll
    for (int j = 0; j < 2; ++j) {
      const int c = wv * 2 + j;                  // 1KB chunk 0..7
      const int r = c * 8 + (lane >> 3);         // local m-row 0..63
      const int g = (lane & 7) ^ (r & 7);
      load_lds16(Abf + (size_t)r * K + k0 + g * 8,
                 (char*)&Alds[buf][0] + c * 1024);
    }
  };

  auto compute = [&](int buf) {
    const int wr = wv * 16 + lrow;               // W local row
#pragma unroll
    for (int kc = 0; kc < 2; ++kc) {
      const int g0 = kc * 8 + lk * 2;
      const float4 wlo = *(const float4*)((const char*)&Wlds[buf][0]
                          + wr * 256 + ((g0 ^ (lrow & 15)) * 16));
      const float4 whi = *(const float4*)((const char*)&Wlds[buf][0]
                          + wr * 256 + (((g0 + 1) ^ (lrow & 15)) * 16));
      const bf16x8 wb = cvt8(wlo, whi);
#pragma unroll
      for (int mf = 0; mf < 4; ++mf) {
        const int ar = mf * 16 + lrow;
        const int ga = ((kc << 2) | lk) ^ (ar & 7);
        const bf16x8 av = *(const bf16x8*)((const char*)&Alds[buf][0]
                           + ar * 128 + ga * 16);
        acc[mf] = __builtin_amdgcn_mfma_f32_16x16x32_bf16(av, wb, acc[mf], 0, 0, 0);
      }
    }
  };

  // prologue: 2 tiles in flight = 12 loads/thread outstanding
  stage(0, kbase);
  stage(1, kbase + 64);

  for (int t = 0; t < NT; ++t) {
    if (t < NT - 1) asm volatile("s_waitcnt vmcnt(6)");   // tile t retired; t+1 flying
    else            asm volatile("s_waitcnt vmcnt(0)");
    __builtin_amdgcn_sched_barrier(0);
    __builtin_amdgcn_s_barrier();     // tile t visible; all waves done compute(t-1)
    __builtin_amdgcn_sched_barrier(0);
    compute(t % 3);
    if (t + 2 <= NT - 1) stage((t + 2) % 3, kbase + (t + 2) * 64);
  }

  // C/D layout: col(lane&15)=n, row=(lane>>4)*4+i=m  [m89-verified]
  float* ob = Outp + (size_t)ks * 64 * N + nblk + wv * 16 + lrow;
#pragma unroll
  for (int mf = 0; mf < 4; ++mf)
#pragma unroll
    for (int i = 0; i < 4; ++i)
      ob[(size_t)(mf * 16 + lk * 4 + i) * N] = acc[mf][i];
}

__device__ __forceinline__ float block_reduce_sum256(float v, float* red, int t) {
#pragma unroll
  for (int o = 32; o > 0; o >>= 1) v += __shfl_xor(v, o, 64);
  __syncthreads();
  if ((t & 63) == 0) red[t >> 6] = v;
  __syncthreads();
  return red[0] + red[1] + red[2] + red[3];
}

// one block per (b, head); 256 threads. proj = sum of 4 split-K partials.
__global__ __launch_bounds__(256) void state_update(
    const float* __restrict__ pp, const float* __restrict__ h,
    const float* __restrict__ B_prev, const float* __restrict__ x_prev,
    const float* __restrict__ theta_cumsum, const float* __restrict__ A_log,
    const float* __restrict__ B_bias, const float* __restrict__ C_bias,
    float* __restrict__ o_h, float* __restrict__ o_B,
    float* __restrict__ o_xp, float* __restrict__ o_th,
    short* __restrict__ ysbf) {
  const int bid = blockIdx.x;            // b*32 + hd
  const int b = bid >> 5, hd = bid & 31;
  const int t = threadIdx.x;
  const size_t pb = (size_t)b * 18496;
#define PJ(o) (pp[pb + (o)] + pp[PSTR + pb + (o)] + pp[2 * PSTR + pb + (o)] \
             + pp[3 * PSTR + pb + (o)])

  __shared__ float sB[128], sC[128], sBp[128], sXp[128], sXv[128];
  __shared__ float red[8];
  __shared__ float yred[8][128];

  float aval = (t < 128) ? expf(A_log[hd * 128 + t]) : 0.f;
  float brv  = (t < 128) ? PJ(8192 + hd * 128 + t) : 0.f;
  float crv  = (t < 128) ? PJ(12288 + hd * 128 + t) : 0.f;
  if (t < 128) {
    sBp[t] = B_prev[(size_t)bid * 128 + t];
    float xp = PJ(hd * 128 + t);
    sXp[t] = xp;
    o_xp[(size_t)bid * 128 + t] = xp;
    sXv[t] = x_prev[(size_t)bid * 128 + t];
  }
  float sumA  = block_reduce_sum256(aval, red, t);
  float sumB2 = block_reduce_sum256(brv * brv, red, t);
  float sumC2 = block_reduce_sum256(crv * crv, red, t);

  const float dt_raw  = PJ(16384 + hd);
  const float lam_raw = PJ(16416 + hd);
  const float dt  = (dt_raw > 20.f) ? dt_raw : log1pf(expf(dt_raw));
  const float lam = 1.f / (1.f + expf(-lam_raw));
  const float A     = -sumA * (1.f / 128.f);
  const float alpha = expf(dt * A);
  const float beta  = (1.f - lam) * dt * alpha;
  const float gamma = lam * dt;
  const float rb = rsqrtf(sumB2 * (1.f / 128.f) + EPSV);
  const float rc = rsqrtf(sumC2 * (1.f / 128.f) + EPSV);

  if (t < 64) {
    float b0 = PJ(8192 + hd * 128 + 2 * t);
    float b1 = PJ(8192 + hd * 128 + 2 * t + 1);
    float c0 = PJ(12288 + hd * 128 + 2 * t);
    float c1 = PJ(12288 + hd * 128 + 2 * t + 1);
    b0 = b0 * rb + B_bias[hd * 128 + 2 * t];
    b1 = b1 * rb + B_bias[hd * 128 + 2 * t + 1];
    c0 = c0 * rc + C_bias[hd * 128 + 2 * t];
    c1 = c1 * rc + C_bias[hd * 128 + 2 * t + 1];
    const float th = theta_cumsum[(size_t)bid * 64 + t]
                   + PJ(16448 + hd * 64 + t) * dt;
    o_th[(size_t)bid * 64 + t] = th;
    const float cth = cosf(th), sth = sinf(th);
    const float nb0 = b0 * cth - b1 * sth, nb1 = b0 * sth + b1 * cth;
    const float nc0 = c0 * cth - c1 * sth, nc1 = c0 * sth + c1 * cth;
    sB[2 * t] = nb0; sB[2 * t + 1] = nb1;
    sC[2 * t] = nc0; sC[2 * t + 1] = nc1;
    o_B[(size_t)bid * 128 + 2 * t] = nb0;
    o_B[(size_t)bid * 128 + 2 * t + 1] = nb1;
  }
  __syncthreads();

  const int p4 = t & 31, nb = t >> 5;
  const float4 xp4 = *(const float4*)&sXp[p4 * 4];
  const float4 xv4 = *(const float4*)&sXv[p4 * 4];
  const size_t hbase = (size_t)bid * 16384;
  float4 ya = {0.f, 0.f, 0.f, 0.f};
  for (int n = nb; n < 128; n += 8) {
    const float4 hv = *(const float4*)&h[hbase + n * 128 + p4 * 4];
    const float cb = gamma * sB[n];
    const float cp = beta * sBp[n];
    float4 hn;
    hn.x = alpha * hv.x + cp * xv4.x + cb * xp4.x;
    hn.y = alpha * hv.y + cp * xv4.y + cb * xp4.y;
    hn.z = alpha * hv.z + cp * xv4.z + cb * xp4.z;
    hn.w = alpha * hv.w + cp * xv4.w + cb * xp4.w;
    *(float4*)&o_h[hbase + n * 128 + p4 * 4] = hn;
    const float cn = sC[n];
    ya.x += cn * hn.x; ya.y += cn * hn.y; ya.z += cn * hn.z; ya.w += cn * hn.w;
  }
  *(float4*)&yred[nb][p4 * 4] = ya;
  __syncthreads();
  if (t < 128) {
    float y = 0.f;
#pragma unroll
    for (int j = 0; j < 8; ++j) y += yred[j][t];
    const float zv = PJ(4096 + hd * 128 + t);
    const float sig = 1.f / (1.f + expf(-zv));
    ysbf[(size_t)b * 4096 + hd * 128 + t] = f2b(y * zv * sig);
  }
#undef PJ
}

// y[64][2048] = sum over 16 K-split partials
__global__ __launch_bounds__(256) void reduce_y(
    const float* __restrict__ yp, float* __restrict__ y, int n4) {
  const int i = blockIdx.x * 256 + threadIdx.x;
  if (i < n4) {
    float4 s = ((const float4*)yp)[i];
#pragma unroll
    for (int k = 1; k < 16; ++k) {
      float4 t = ((const float4*)(yp + (size_t)k * 131072))[i];
      s.x += t.x; s.y += t.y; s.z += t.z; s.w += t.w;
    }
    ((float4*)y)[i] = s;
  }
}

extern "C" void kernel_launch(void* const* d_in, const int* in_sizes, int n_in,
                              void* d_out, int out_size, void* d_ws, size_t ws_size,
                              hipStream_t stream) {
  const float* x            = (const float*)d_in[0];
  const float* h            = (const float*)d_in[1];
  const float* B_prev       = (const float*)d_in[2];
  const float* x_prev       = (const float*)d_in[3];
  const float* theta_cumsum = (const float*)d_in[4];
  const float* W_in         = (const float*)d_in[5];
  const float* A_log        = (const float*)d_in[6];
  const float* B_bias       = (const float*)d_in[7];
  const float* C_bias       = (const float*)d_in[8];
  const float* W_out        = (const float*)d_in[9];

  float* out  = (float*)d_out;
  float* o_y  = out;                        // 64*2048
  float* o_h  = out + 131072;               // 64*32*128*128
  float* o_B  = o_h + 33554432;             // 64*32*128
  float* o_xp = o_B + 262144;               // 64*32*128
  float* o_th = o_xp + 262144;              // 64*32*64

  // ws layout
  float* pp   = (float*)d_ws;               // 4 x PSTR fp32 split-K partials
  float* yp   = pp;                         // 16 x 131072 fp32 (reuse after SU)
  short* xbf  = (short*)(pp + 4 * PSTR);    // 64*2048 bf16
  short* ysbf = xbf + 131072;               // 64*4096 bf16

  // 1) x -> bf16
  conv_bf16<<<dim3(64), dim3(256), 0, stream>>>(x, xbf, 16384);
  // 2) proj partials = xbf @ W_in^T  (N=18496, K=2048, KSPLIT=4, NT=8)
  gemm_wlds<4, 8><<<dim3(289 * 4), dim3(256), 0, stream>>>(
      xbf, W_in, pp, 18496, 2048);
  // 3) fused state update (sums 4 partials at load)
  state_update<<<dim3(2048), dim3(256), 0, stream>>>(
      pp, h, B_prev, x_prev, theta_cumsum, A_log, B_bias, C_bias,
      o_h, o_B, o_xp, o_th, ysbf);
  // 4) y partials = ysbf @ W_out^T   (N=2048, K=4096, KSPLIT=16, NT=4)
  gemm_wlds<16, 4><<<dim3(32 * 16), dim3(256), 0, stream>>>(
      ysbf, W_out, yp, 2048, 4096);
  // 5) final y reduce
  reduce_y<<<dim3(128), dim3(256), 0, stream>>>(yp, o_y, 32768);
}